// Round 1
// baseline (38.106 us; speedup 1.0000x reference)
//
#include <hip/hip_runtime.h>
#include <hip/hip_bf16.h>

// Problem: B=8192, A=128, F=16, S=8
// x[b,a,:] = c[b,a,:] - q[b,a,:] * lam[b, seg[b,a]]
// lam[b,s] = (sum_{a: seg=s} c.q - charges[b,s]) / (sum_{a: seg=s} q.q)

#define B_ 8192
#define A_ 128
#define F_ 16
#define S_ 8

__global__ __launch_bounds__(A_) void qp_seg_norm_kernel(
    const float* __restrict__ c_iso,
    const float* __restrict__ int_iso,
    const int*   __restrict__ segment,
    const float* __restrict__ charges,
    float*       __restrict__ out)
{
    const int b = blockIdx.x;        // batch index
    const int a = threadIdx.x;       // atom index 0..127

    __shared__ float s_qc[S_];
    __shared__ float s_qq[S_];
    __shared__ float s_lam[S_];

    if (a < S_) { s_qc[a] = 0.0f; s_qq[a] = 0.0f; }
    __syncthreads();

    const size_t base = ((size_t)b * A_ + a) * F_;   // 16 floats per atom, 64B aligned
    const float4* cp = reinterpret_cast<const float4*>(c_iso + base);
    const float4* qp = reinterpret_cast<const float4*>(int_iso + base);

    float4 cv[4], qv[4];
#pragma unroll
    for (int j = 0; j < 4; ++j) { cv[j] = cp[j]; qv[j] = qp[j]; }

    float cq = 0.0f, qq = 0.0f;
#pragma unroll
    for (int j = 0; j < 4; ++j) {
        cq += cv[j].x * qv[j].x + cv[j].y * qv[j].y
            + cv[j].z * qv[j].z + cv[j].w * qv[j].w;
        qq += qv[j].x * qv[j].x + qv[j].y * qv[j].y
            + qv[j].z * qv[j].z + qv[j].w * qv[j].w;
    }

    const int s = segment[(size_t)b * A_ + a];
    atomicAdd(&s_qc[s], cq);
    atomicAdd(&s_qq[s], qq);
    __syncthreads();

    if (a < S_) {
        const float charge = charges[(size_t)b * S_ + a];
        s_lam[a] = (s_qc[a] - charge) / s_qq[a];
    }
    __syncthreads();

    const float lam = s_lam[s];

    float4* op = reinterpret_cast<float4*>(out + base);
#pragma unroll
    for (int j = 0; j < 4; ++j) {
        float4 r;
        r.x = cv[j].x - qv[j].x * lam;
        r.y = cv[j].y - qv[j].y * lam;
        r.z = cv[j].z - qv[j].z * lam;
        r.w = cv[j].w - qv[j].w * lam;
        op[j] = r;
    }
}

extern "C" void kernel_launch(void* const* d_in, const int* in_sizes, int n_in,
                              void* d_out, int out_size, void* d_ws, size_t ws_size,
                              hipStream_t stream) {
    const float* c_iso   = (const float*)d_in[0];
    const float* int_iso = (const float*)d_in[1];
    const int*   segment = (const int*)d_in[2];
    const float* charges = (const float*)d_in[3];
    float* out = (float*)d_out;

    qp_seg_norm_kernel<<<B_, A_, 0, stream>>>(c_iso, int_iso, segment, charges, out);
}